// Round 1
// baseline (190.818 us; speedup 1.0000x reference)
//
#include <hip/hip_runtime.h>
#include <hip/hip_bf16.h>

typedef __bf16 bf16;
typedef bf16  bf16x4 __attribute__((ext_vector_type(4)));
typedef bf16  bf16x8 __attribute__((ext_vector_type(8)));
typedef float f32x4  __attribute__((ext_vector_type(4)));

union B8 { bf16x8 v; bf16 e[8]; };
union B4 { bf16x4 v; bf16 e[4]; };
union F4 { f32x4 v; float e[4]; };

// Async global->LDS DMA, 16 B per lane (wave-uniform LDS base, lane i ->
// base + i*16).
#define GLOAD_LDS16(g, l)                                            \
  __builtin_amdgcn_global_load_lds(                                  \
      (const __attribute__((address_space(1))) void*)(g),            \
      (__attribute__((address_space(3))) void*)(l), 16, 0, 0)

// Swizzled tile: row stride 64 bf16, 16B chunk p = c8 ^ (row & 7).
#define SWZ(arr, R, c8) (*(const bf16x8*)&(arr)[(size_t)(R) * 64 + (((c8) ^ ((R) & 7)) << 3)])

// ---------------------------------------------------------------------------
// Kernel 0: weight conversion fp32 -> bf16. q/k rows scaled by
// 0.35355339 * sqrt(log2(e)) = 0.42468158 -> scores arrive in log2 domain.
// ---------------------------------------------------------------------------
__global__ __launch_bounds__(256) void conv_w_kernel(
    const float* __restrict__ qkvw, const float* __restrict__ qkvb,
    const float* __restrict__ pw,
    bf16* __restrict__ Wb, bf16* __restrict__ Pb, float* __restrict__ bs)
{
  const int row = blockIdx.x;
  const int tid = threadIdx.x;
  if (row < 3072) {
    const float s = ((row % 192) < 128) ? 0.42468158f : 1.0f;
    const float4 a = ((const float4*)(qkvw + (size_t)row * 1024))[tid];
    B4 o;
    o.e[0] = (bf16)(a.x * s); o.e[1] = (bf16)(a.y * s);
    o.e[2] = (bf16)(a.z * s); o.e[3] = (bf16)(a.w * s);
    ((bf16x4*)(Wb + (size_t)row * 1024))[tid] = o.v;
    if (tid == 0) bs[row] = qkvb[row] * s;
  } else {
    const int r = row - 3072;
    const float4 a = ((const float4*)(pw + (size_t)r * 1024))[tid];
    B4 o;
    o.e[0] = (bf16)a.x; o.e[1] = (bf16)a.y;
    o.e[2] = (bf16)a.z; o.e[3] = (bf16)a.w;
    ((bf16x4*)(Pb + (size_t)r * 1024))[tid] = o.v;
  }
}

// ---------------------------------------------------------------------------
// Kernel 1: GroupNorm, transposed output: x[b][c][t] fp32 -> xnt[b][t][c] bf16.
// ---------------------------------------------------------------------------
__global__ __launch_bounds__(256) void gn_t_kernel(
    const float* __restrict__ x, const float* __restrict__ w,
    const float* __restrict__ bias, bf16* __restrict__ xnt)
{
  const int blk = blockIdx.x;
  const int b = blk >> 5, g = blk & 31;
  const float* xp = x + (size_t)(b * 1024 + g * 32) * 1024;
  const int tid = threadIdx.x;

  float s = 0.f, ss = 0.f;
  for (int ch = tid; ch < 4096; ch += 256) {
    const float4* p = (const float4*)(xp + (size_t)ch * 8);
    float4 u0 = p[0], u1 = p[1];
    s  += u0.x + u0.y + u0.z + u0.w + u1.x + u1.y + u1.z + u1.w;
    ss += u0.x*u0.x + u0.y*u0.y + u0.z*u0.z + u0.w*u0.w
        + u1.x*u1.x + u1.y*u1.y + u1.z*u1.z + u1.w*u1.w;
  }
  #pragma unroll
  for (int m = 1; m < 64; m <<= 1) { s += __shfl_xor(s, m); ss += __shfl_xor(ss, m); }

  __shared__ float red[8];
  __shared__ float stats[2];
  const int wave = tid >> 6, lane = tid & 63;
  if (lane == 0) { red[wave] = s; red[4 + wave] = ss; }
  __syncthreads();
  if (tid == 0) {
    float ts  = red[0] + red[1] + red[2] + red[3];
    float tss = red[4] + red[5] + red[6] + red[7];
    float mu  = ts * (1.f / 32768.f);
    float var = tss * (1.f / 32768.f) - mu * mu;
    stats[0] = mu;
    stats[1] = rsqrtf(var + 1e-5f);
  }
  __syncthreads();
  const float mu = stats[0], rs = stats[1];

  for (int ti = 0; ti < 4; ++ti) {
    const int t = ti * 256 + tid;
    B8 o[4];
    #pragma unroll
    for (int cc = 0; cc < 32; ++cc) {
      const float wt = w[g * 32 + cc] * rs;
      const float bsv = bias[g * 32 + cc];
      const float v = xp[(size_t)cc * 1024 + t];
      o[cc >> 3].e[cc & 7] = (bf16)((v - mu) * wt + bsv);
    }
    bf16* dst = xnt + (size_t)(b * 1024 + t) * 1024 + g * 32;
    #pragma unroll
    for (int j = 0; j < 4; ++j) *(bf16x8*)(dst + j * 8) = o[j].v;
  }
}

// ---------------------------------------------------------------------------
// Kernel 2: merged qkv GEMM, 256x256 tile / BK=64 / 8-phase counted-vmcnt
// schedule (T2+T3+T4+T5). M = 4096 (b,t fused), N = 3072, K = 1024.
// Grid 12x16 = 192 blocks (XCD-chunked swizzle, 192 % 8 == 0), 512 threads
// = 8 waves (2M x 4N), wave tile 128x64. LDS 2 x (256x64) x 2 mat = 128 KB.
//
// Per K-tile (4 phases, 16 MFMA each):
//   ph0: ds_read B (8, held in regs for whole tile) + A mt0,1; issue next
//        tile's A1,A3 (its A blocks 1,3 were last read in prev tile ph2/3)
//   ph1: ds_read A mt2,3; issue tile t+2's B0,B1 (cur B consumed in ph0)
//   ph2: ds_read A mt4,5; issue tile t+2's B2,B3
//   ph3: ds_read A mt6,7; issue tile t+2's A0,A2 (cur A blk 0,2 done ph1);
//        s_waitcnt vmcnt(6) -> next tile fully landed, 6 loads in flight.
// Every phase: barrier; lgkmcnt(0); setprio(1); 16 MFMA; setprio(0); barrier.
// Accumulation order over K identical to the previous kernel.
// ---------------------------------------------------------------------------
__global__ __launch_bounds__(512, 2) void gemm_qkv_kernel(
    const bf16* __restrict__ xnt, const bf16* __restrict__ Wb,
    const float* __restrict__ bs, bf16* __restrict__ qkT, bf16* __restrict__ vv)
{
  const int bid = blockIdx.x;
  const int swz = (bid & 7) * 24 + (bid >> 3);   // bijective: 192 = 8 * 24
  const int bxn = swz % 12, bym = swz / 12;
  const int n0 = bxn * 256, m0 = bym * 256;

  __shared__ __align__(16) bf16 Al[2][256 * 64];
  __shared__ __align__(16) bf16 Bl[2][256 * 64];

  const int tid  = threadIdx.x;
  const int wave = tid >> 6, lane = tid & 63;
  const int quad = lane >> 4, l15 = lane & 15;
  const int wr = wave >> 2, wc = wave & 3;
  const int lrow = lane >> 3, lp = lane & 7;
  const int sc8 = (lp ^ lrow) << 3;   // pre-swizzled source chunk (elements)

  // One DMA call: 64 rows (8 per wave), wave-linear LDS dest, swizzled src.
  #define STAGE_A(bufn, kt, c)                                               \
    GLOAD_LDS16(xnt + (size_t)(m0 + (c) * 64 + wave * 8 + lrow) * 1024 +     \
                    (kt) * 64 + sc8,                                         \
                &Al[bufn][((c) * 64 + wave * 8) * 64])
  #define STAGE_B(bufn, kt, c)                                               \
    GLOAD_LDS16(Wb + (size_t)(n0 + (c) * 64 + wave * 8 + lrow) * 1024 +      \
                    (kt) * 64 + sc8,                                         \
                &Bl[bufn][((c) * 64 + wave * 8) * 64])

  F4 acc[8][4];
  #pragma unroll
  for (int i = 0; i < 8; ++i)
    #pragma unroll
    for (int j = 0; j < 4; ++j) acc[i][j].v = (f32x4){0.f, 0.f, 0.f, 0.f};

  // Prologue: tile0 complete (8 loads) + tile1 {B0..B3, A0, A2} (6 loads).
  #pragma unroll
  for (int c = 0; c < 4; ++c) STAGE_A(0, 0, c);
  #pragma unroll
  for (int c = 0; c < 4; ++c) STAGE_B(0, 0, c);
  #pragma unroll
  for (int c = 0; c < 4; ++c) STAGE_B(1, 1, c);
  STAGE_A(1, 1, 0); STAGE_A(1, 1, 2);
  asm volatile("s_waitcnt vmcnt(6)" ::: "memory");   // tile0 landed
  __builtin_amdgcn_s_barrier();
  asm volatile("" ::: "memory");

  bf16x8 bfrag[2][4];   // B fragments live across the whole K-tile

  for (int t = 0; t < 16; ++t) {
    const int cb = t & 1, nb = cb ^ 1;
    #pragma unroll
    for (int ph = 0; ph < 4; ++ph) {
      if (ph == 0) {
        #pragma unroll
        for (int kk = 0; kk < 2; ++kk)
          #pragma unroll
          for (int nt = 0; nt < 4; ++nt)
            bfrag[kk][nt] = SWZ(Bl[cb], wc * 64 + nt * 16 + l15, kk * 4 + quad);
      }
      bf16x8 af[2][2];
      #pragma unroll
      for (int i = 0; i < 2; ++i)
        #pragma unroll
        for (int kk = 0; kk < 2; ++kk)
          af[i][kk] = SWZ(Al[cb], wr * 128 + (2 * ph + i) * 16 + l15, kk * 4 + quad);

      if (ph == 0 && t + 1 < 16) { STAGE_A(nb, t + 1, 1); STAGE_A(nb, t + 1, 3); }
      if (ph == 1 && t + 2 < 16) { STAGE_B(cb, t + 2, 0); STAGE_B(cb, t + 2, 1); }
      if (ph == 2 && t + 2 < 16) { STAGE_B(cb, t + 2, 2); STAGE_B(cb, t + 2, 3); }
      if (ph == 3 && t + 2 < 16) { STAGE_A(cb, t + 2, 0); STAGE_A(cb, t + 2, 2); }

      asm volatile("" ::: "memory");
      __builtin_amdgcn_s_barrier();
      asm volatile("s_waitcnt lgkmcnt(0)" ::: "memory");
      __builtin_amdgcn_sched_barrier(0);

      __builtin_amdgcn_s_setprio(1);
      #pragma unroll
      for (int kk = 0; kk < 2; ++kk)
        #pragma unroll
        for (int i = 0; i < 2; ++i)
          #pragma unroll
          for (int nt = 0; nt < 4; ++nt)
            acc[2 * ph + i][nt].v = __builtin_amdgcn_mfma_f32_16x16x32_bf16(
                af[i][kk], bfrag[kk][nt], acc[2 * ph + i][nt].v, 0, 0, 0);
      __builtin_amdgcn_s_setprio(0);

      if (ph == 3) {
        if (t < 14)       asm volatile("s_waitcnt vmcnt(6)" ::: "memory");
        else if (t == 14) asm volatile("s_waitcnt vmcnt(0)" ::: "memory");
      }
      asm volatile("" ::: "memory");
      __builtin_amdgcn_s_barrier();
      asm volatile("" ::: "memory");
    }
  }
  #undef STAGE_A
  #undef STAGE_B

  // Epilogue: same split as before; block spans one z (256-aligned M chunk).
  #pragma unroll
  for (int nt = 0; nt < 4; ++nt) {
    const int base = n0 + wc * 64 + nt * 16;
    const int r192 = base % 192, head = base / 192;
    const float bb = bs[base + l15];
    if (r192 < 128) {
      const int col = head * 128 + r192 + l15;
      #pragma unroll
      for (int mt = 0; mt < 8; ++mt)
        #pragma unroll
        for (int r = 0; r < 4; ++r) {
          const int m = m0 + wr * 128 + mt * 16 + quad * 4 + r;
          qkT[(size_t)m * 2048 + col] = (bf16)(acc[mt][nt].e[r] + bb);
        }
    } else {
      const int z = m0 >> 10;
      bf16* vrow = vv + ((size_t)z * 1024 + head * 64 + (r192 - 128) + l15) * 1024;
      const int tb = (m0 & 1023) + wr * 128;
      #pragma unroll
      for (int mt = 0; mt < 8; ++mt) {
        B4 pk;
        #pragma unroll
        for (int r = 0; r < 4; ++r) pk.e[r] = (bf16)(acc[mt][nt].e[r] + bb);
        *(bf16x4*)&vrow[tb + mt * 16 + quad * 4] = pk.v;
      }
    }
  }
}

// ---------------------------------------------------------------------------
// Kernel 4: proj GEMM, 64x64 tiles -> grid (16,16,4) = 1024 blocks = 4/CU
// (was grid-limited at 2/CU). DMA staging + swizzled LDS, BK=64.
// Wave-tile 32x32 (2x2 MFMA frags). out = acc + bias + residual (fp32).
// ---------------------------------------------------------------------------
__global__ __launch_bounds__(256) void gemm_proj_kernel(
    const bf16* __restrict__ Pb, const bf16* __restrict__ Bt,
    float* __restrict__ Cf, const float* __restrict__ bias,
    const float* __restrict__ resf)
{
  const int z = blockIdx.z;
  Bt   += (size_t)z * 1024 * 1024;
  Cf   += (size_t)z * 1024 * 1024;
  resf += (size_t)z * 1024 * 1024;
  const int n0 = blockIdx.x * 64, m0 = blockIdx.y * 64;

  __shared__ __align__(16) bf16 Al[64 * 64];
  __shared__ __align__(16) bf16 Bl[64 * 64];

  const int tid  = threadIdx.x;
  const int wave = tid >> 6, lane = tid & 63;
  const int quad = lane >> 4, l15 = lane & 15;
  const int wr = wave >> 1, wc = wave & 1;
  const int lrow = lane >> 3, lp = lane & 7;

  F4 acc[2][2];
  #pragma unroll
  for (int i = 0; i < 2; ++i)
    #pragma unroll
    for (int j = 0; j < 2; ++j) acc[i][j].v = (f32x4){0.f, 0.f, 0.f, 0.f};

  for (int k0 = 0; k0 < 1024; k0 += 64) {
    #pragma unroll
    for (int call = 0; call < 2; ++call) {
      const int row = wave * 16 + call * 8 + lrow;
      const int c8  = lp ^ (row & 7);
      GLOAD_LDS16(Pb + (size_t)(m0 + row) * 1024 + k0 + c8 * 8,
                  &Al[(wave * 16 + call * 8) * 64]);
      GLOAD_LDS16(Bt + (size_t)(n0 + row) * 1024 + k0 + c8 * 8,
                  &Bl[(wave * 16 + call * 8) * 64]);
    }
    __syncthreads();

    #pragma unroll
    for (int ks = 0; ks < 2; ++ks) {
      bf16x8 af[2], bfr[2];
      #pragma unroll
      for (int mt = 0; mt < 2; ++mt)
        af[mt] = SWZ(Al, wr * 32 + mt * 16 + l15, ks * 4 + quad);
      #pragma unroll
      for (int nt = 0; nt < 2; ++nt)
        bfr[nt] = SWZ(Bl, wc * 32 + nt * 16 + l15, ks * 4 + quad);
      #pragma unroll
      for (int mt = 0; mt < 2; ++mt)
        #pragma unroll
        for (int nt = 0; nt < 2; ++nt)
          acc[mt][nt].v = __builtin_amdgcn_mfma_f32_16x16x32_bf16(
              af[mt], bfr[nt], acc[mt][nt].v, 0, 0, 0);
    }
    __syncthreads();
  }

  #pragma unroll
  for (int mt = 0; mt < 2; ++mt) {
    #pragma unroll
    for (int r = 0; r < 4; ++r) {
      const int m = m0 + wr * 32 + mt * 16 + quad * 4 + r;
      const float bb = bias[m];
      #pragma unroll
      for (int nt = 0; nt < 2; ++nt) {
        const int n = n0 + wc * 32 + nt * 16 + l15;
        Cf[(size_t)m * 1024 + n] = acc[mt][nt].e[r] + bb + resf[(size_t)m * 1024 + n];
      }
    }
  }
}

// ---------------------------------------------------------------------------
// Kernel 3: attention, S^T + no-max softmax, 128-t blocks: each wave owns
// TWO independent 16-t bands -> k/v fragments read ONCE per wave-chunk and
// reused by both bands, two independent S->exp->PV chains interleave for
// latency hiding, k/v staged per 128 t. grid (16,8,4) = 512 blocks.
// LDS: qP 16K (q then P bands) + kl 2x8K + vl 2x8K = 48 KB.
// ---------------------------------------------------------------------------
__global__ __launch_bounds__(256) void attn_kernel(
    const bf16* __restrict__ qkTin, const bf16* __restrict__ vmat,
    bf16* __restrict__ aout)
{
  const int h = blockIdx.x, tt = blockIdx.y, z = blockIdx.z;
  const bf16* qk = qkTin + (size_t)z * 1024 * 2048;
  const bf16* vp = vmat + (size_t)z * 1024 * 1024 + (size_t)(h * 64) * 1024;
  aout += (size_t)z * 1024 * 1024;
  const int t0 = tt * 128;

  __shared__ __align__(16) bf16 qP[128 * 64];     // q rows (init) then P bands
  __shared__ __align__(16) bf16 kl[2][64 * 64];
  __shared__ __align__(16) bf16 vl[2][64 * 64];

  const int tid  = threadIdx.x;
  const int wave = tid >> 6, lane = tid & 63;
  const int quad = lane >> 4, l15 = lane & 15;
  const int lrow = lane >> 3, lp = lane & 7;

  #pragma unroll
  for (int c = 0; c < 4; ++c) {
    const int row = wave * 32 + c * 8 + lrow;
    const int c8  = lp ^ (row & 7);
    GLOAD_LDS16(qk + (size_t)(t0 + row) * 2048 + h * 128 + c8 * 8,
                &qP[(wave * 32 + c * 8) * 64]);
  }
  const int r0 = wave * 16 + lrow, r1 = wave * 16 + 8 + lrow;
  const int c80 = lp ^ (r0 & 7), c81 = lp ^ (r1 & 7);
  GLOAD_LDS16(qk + (size_t)r0 * 2048 + h * 128 + 64 + c80 * 8, &kl[0][(wave * 16) * 64]);
  GLOAD_LDS16(qk + (size_t)r1 * 2048 + h * 128 + 64 + c81 * 8, &kl[0][(wave * 16 + 8) * 64]);
  GLOAD_LDS16(vp + (size_t)r0 * 1024 + c80 * 8, &vl[0][(wave * 16) * 64]);
  GLOAD_LDS16(vp + (size_t)r1 * 1024 + c81 * 8, &vl[0][(wave * 16 + 8) * 64]);
  __syncthreads();

  bf16x8 bq0[2], bq1[2];
  int prow[2];
  #pragma unroll
  for (int b = 0; b < 2; ++b) {
    const int Rq = wave * 32 + b * 16 + l15;
    bq0[b] = SWZ(qP, Rq, quad);
    bq1[b] = SWZ(qP, Rq, quad + 4);
    prow[b] = Rq;
  }

  float l_i[2] = {0.f, 0.f};
  F4 oacc[2][4];
  #pragma unroll
  for (int b = 0; b < 2; ++b)
    #pragma unroll
    for (int ct = 0; ct < 4; ++ct) oacc[b][ct].v = (f32x4){0.f, 0.f, 0.f, 0.f};

  const int pq8 = (quad & 1) * 4;

  int buf = 0;
  for (int s0 = 0; s0 < 1024; s0 += 64) {
    if (s0 + 64 < 1024) {
      const int nb = buf ^ 1, sn = s0 + 64;
      GLOAD_LDS16(qk + (size_t)(sn + r0) * 2048 + h * 128 + 64 + c80 * 8,
                  &kl[nb][(wave * 16) * 64]);
      GLOAD_LDS16(qk + (size_t)(sn + r1) * 2048 + h * 128 + 64 + c81 * 8,
                  &kl[nb][(wave * 16 + 8) * 64]);
      GLOAD_LDS16(vp + (size_t)r0 * 1024 + sn + c80 * 8, &vl[nb][(wave * 16) * 64]);
      GLOAD_LDS16(vp + (size_t)r1 * 1024 + sn + c81 * 8, &vl[nb][(wave * 16 + 8) * 64]);
    }

    bf16x8 ak0[4], ak1[4], bv[2][4];
    #pragma unroll
    for (int st = 0; st < 4; ++st) {
      const int Rk = st * 16 + l15;
      ak0[st] = SWZ(kl[buf], Rk, quad);
      ak1[st] = SWZ(kl[buf], Rk, quad + 4);
    }
    #pragma unroll
    for (int ks = 0; ks < 2; ++ks)
      #pragma unroll
      for (int ct = 0; ct < 4; ++ct)
        bv[ks][ct] = SWZ(vl[buf], ct * 16 + l15, ks * 4 + quad);

    #pragma unroll
    for (int b = 0; b < 2; ++b) {
      F4 sacc[4];
      #pragma unroll
      for (int st = 0; st < 4; ++st) sacc[st].v = (f32x4){0.f, 0.f, 0.f, 0.f};
      #pragma unroll
      for (int st = 0; st < 4; ++st) {
        sacc[st].v = __builtin_amdgcn_mfma_f32_16x16x32_bf16(ak0[st], bq0[b], sacc[st].v, 0, 0, 0);
        sacc[st].v = __builtin_amdgcn_mfma_f32_16x16x32_bf16(ak1[st], bq1[b], sacc[st].v, 0, 0, 0);
      }

      bf16* const pbase = &qP[(size_t)prow[b] * 64];
      #pragma unroll
      for (int st = 0; st < 4; ++st) {
        B4 pk;
        #pragma unroll
        for (int r = 0; r < 4; ++r) {
          const float p = __builtin_amdgcn_exp2f(sacc[st].e[r]);
          l_i[b] += p;
          pk.e[r] = (bf16)p;
        }
        const int c8 = (st * 2 + (quad >> 1)) ^ (prow[b] & 7);
        *(bf16x4*)(pbase + (c8 << 3) + pq8) = pk.v;
      }

      #pragma unroll
      for (int ks = 0; ks < 2; ++ks) {
        const bf16x8 ap = SWZ(qP, prow[b], ks * 4 + quad);
        #pragma unroll
        for (int ct = 0; ct < 4; ++ct)
          oacc[b][ct].v = __builtin_amdgcn_mfma_f32_16x16x32_bf16(
              ap, bv[ks][ct], oacc[b][ct].v, 0, 0, 0);
      }
    }
    __syncthreads();
    buf ^= 1;
  }

  #pragma unroll
  for (int b = 0; b < 2; ++b) {
    float li = l_i[b];
    li += __shfl_xor(li, 16);
    li += __shfl_xor(li, 32);
    const float inv = 1.f / li;
    float iv[4];
    #pragma unroll
    for (int r = 0; r < 4; ++r) iv[r] = __shfl(inv, quad * 4 + r);
    #pragma unroll
    for (int r = 0; r < 4; ++r) {
      const int t = t0 + wave * 32 + b * 16 + quad * 4 + r;
      #pragma unroll
      for (int ct = 0; ct < 4; ++ct)
        aout[(size_t)t * 1024 + h * 64 + ct * 16 + l15] = (bf16)(oacc[b][ct].e[r] * iv[r]);
    }
  }
}

// ---------------------------------------------------------------------------
// ws layout:
//   xnt [b][t][c] : ws[ 0,  8 MB)
//   qkT [b][t][n] : ws[ 8, 24 MB)
//   v   [b][ov][t]: ws[24, 32 MB)
//   a^T [b][t][c] : ws[32, 40 MB)
//   Wb / Pb / bs  : ws[40, 48 MB) + 12 KB
// ---------------------------------------------------------------------------
extern "C" void kernel_launch(void* const* d_in, const int* in_sizes, int n_in,
                              void* d_out, int out_size, void* d_ws, size_t ws_size,
                              hipStream_t stream)
{
  const float* x    = (const float*)d_in[0];
  const float* nw   = (const float*)d_in[1];
  const float* nb   = (const float*)d_in[2];
  const float* qkvw = (const float*)d_in[3];
  const float* qkvb = (const float*)d_in[4];
  const float* pw   = (const float*)d_in[5];
  const float* pb   = (const float*)d_in[6];
  float* out = (float*)d_out;

  const long M1 = 1024L * 1024L;
  bf16*  xnt = (bf16*)d_ws;
  bf16*  qkT = xnt + 4 * M1;
  bf16*  vv  = xnt + 12 * M1;
  bf16*  at  = xnt + 16 * M1;
  bf16*  Wb  = xnt + 20 * M1;
  bf16*  Pb  = xnt + 23 * M1;
  float* bs  = (float*)(xnt + 24 * M1);

  conv_w_kernel<<<dim3(4096), dim3(256), 0, stream>>>(qkvw, qkvb, pw, Wb, Pb, bs);
  gn_t_kernel<<<dim3(128), dim3(256), 0, stream>>>(x, nw, nb, xnt);
  gemm_qkv_kernel<<<dim3(192), dim3(512), 0, stream>>>(xnt, Wb, bs, qkT, vv);
  attn_kernel<<<dim3(16, 8, 4), dim3(256), 0, stream>>>(qkT, vv, at);
  gemm_proj_kernel<<<dim3(16, 16, 4), dim3(256), 0, stream>>>(Pb, at, out, pb, x);
}

// Round 2
// 176.123 us; speedup vs baseline: 1.0834x; 1.0834x over previous
//
#include <hip/hip_runtime.h>
#include <hip/hip_bf16.h>

typedef __bf16 bf16;
typedef bf16  bf16x4 __attribute__((ext_vector_type(4)));
typedef bf16  bf16x8 __attribute__((ext_vector_type(8)));
typedef float f32x4  __attribute__((ext_vector_type(4)));

union B8 { bf16x8 v; bf16 e[8]; };
union B4 { bf16x4 v; bf16 e[4]; };
union F4 { f32x4 v; float e[4]; };

// Async global->LDS DMA, 16 B per lane (wave-uniform LDS base, lane i ->
// base + i*16).
#define GLOAD_LDS16(g, l)                                            \
  __builtin_amdgcn_global_load_lds(                                  \
      (const __attribute__((address_space(1))) void*)(g),            \
      (__attribute__((address_space(3))) void*)(l), 16, 0, 0)

// Swizzled tile: row stride 64 bf16, 16B chunk p = c8 ^ (row & 7).
#define SWZ(arr, R, c8) (*(const bf16x8*)&(arr)[(size_t)(R) * 64 + (((c8) ^ ((R) & 7)) << 3)])

// ---------------------------------------------------------------------------
// Kernel 0: weight conversion fp32 -> bf16. q/k rows scaled by
// 0.35355339 * sqrt(log2(e)) = 0.42468158 -> scores arrive in log2 domain.
// ---------------------------------------------------------------------------
__global__ __launch_bounds__(256) void conv_w_kernel(
    const float* __restrict__ qkvw, const float* __restrict__ qkvb,
    const float* __restrict__ pw,
    bf16* __restrict__ Wb, bf16* __restrict__ Pb, float* __restrict__ bs)
{
  const int row = blockIdx.x;
  const int tid = threadIdx.x;
  if (row < 3072) {
    const float s = ((row % 192) < 128) ? 0.42468158f : 1.0f;
    const float4 a = ((const float4*)(qkvw + (size_t)row * 1024))[tid];
    B4 o;
    o.e[0] = (bf16)(a.x * s); o.e[1] = (bf16)(a.y * s);
    o.e[2] = (bf16)(a.z * s); o.e[3] = (bf16)(a.w * s);
    ((bf16x4*)(Wb + (size_t)row * 1024))[tid] = o.v;
    if (tid == 0) bs[row] = qkvb[row] * s;
  } else {
    const int r = row - 3072;
    const float4 a = ((const float4*)(pw + (size_t)r * 1024))[tid];
    B4 o;
    o.e[0] = (bf16)a.x; o.e[1] = (bf16)a.y;
    o.e[2] = (bf16)a.z; o.e[3] = (bf16)a.w;
    ((bf16x4*)(Pb + (size_t)r * 1024))[tid] = o.v;
  }
}

// ---------------------------------------------------------------------------
// Kernel 1: GroupNorm, transposed output: x[b][c][t] fp32 -> xnt[b][t][c] bf16.
// ---------------------------------------------------------------------------
__global__ __launch_bounds__(256) void gn_t_kernel(
    const float* __restrict__ x, const float* __restrict__ w,
    const float* __restrict__ bias, bf16* __restrict__ xnt)
{
  const int blk = blockIdx.x;
  const int b = blk >> 5, g = blk & 31;
  const float* xp = x + (size_t)(b * 1024 + g * 32) * 1024;
  const int tid = threadIdx.x;

  float s = 0.f, ss = 0.f;
  for (int ch = tid; ch < 4096; ch += 256) {
    const float4* p = (const float4*)(xp + (size_t)ch * 8);
    float4 u0 = p[0], u1 = p[1];
    s  += u0.x + u0.y + u0.z + u0.w + u1.x + u1.y + u1.z + u1.w;
    ss += u0.x*u0.x + u0.y*u0.y + u0.z*u0.z + u0.w*u0.w
        + u1.x*u1.x + u1.y*u1.y + u1.z*u1.z + u1.w*u1.w;
  }
  #pragma unroll
  for (int m = 1; m < 64; m <<= 1) { s += __shfl_xor(s, m); ss += __shfl_xor(ss, m); }

  __shared__ float red[8];
  __shared__ float stats[2];
  const int wave = tid >> 6, lane = tid & 63;
  if (lane == 0) { red[wave] = s; red[4 + wave] = ss; }
  __syncthreads();
  if (tid == 0) {
    float ts  = red[0] + red[1] + red[2] + red[3];
    float tss = red[4] + red[5] + red[6] + red[7];
    float mu  = ts * (1.f / 32768.f);
    float var = tss * (1.f / 32768.f) - mu * mu;
    stats[0] = mu;
    stats[1] = rsqrtf(var + 1e-5f);
  }
  __syncthreads();
  const float mu = stats[0], rs = stats[1];

  for (int ti = 0; ti < 4; ++ti) {
    const int t = ti * 256 + tid;
    B8 o[4];
    #pragma unroll
    for (int cc = 0; cc < 32; ++cc) {
      const float wt = w[g * 32 + cc] * rs;
      const float bsv = bias[g * 32 + cc];
      const float v = xp[(size_t)cc * 1024 + t];
      o[cc >> 3].e[cc & 7] = (bf16)((v - mu) * wt + bsv);
    }
    bf16* dst = xnt + (size_t)(b * 1024 + t) * 1024 + g * 32;
    #pragma unroll
    for (int j = 0; j < 4; ++j) *(bf16x8*)(dst + j * 8) = o[j].v;
  }
}

// ---------------------------------------------------------------------------
// Kernel 2: merged qkv GEMM. Tile 256x192 -> grid 16x16 = 256 blocks = exactly
// 1 block/CU (fixes the 25% idle CUs of the 192-block 256x256 variant).
// Minimal 2-phase pipeline (verified recipe): per K-tile, issue ALL ds_reads
// of the current buffer FIRST (so no ds_read follows a same-tile DMA in
// program order -> waitcnt pass cannot insert a conservative mid-tile vmcnt
// drain), then issue next tile's 7 global_load_lds into buf^1, then the 48
// MFMAs, then one __syncthreads (vmcnt drain = next tile landed + current
// buffer free). One barrier per K-tile. 8 waves (2M x 4N), wave tile 128x48.
// Each N-tile (192 cols) = one head group -> uniform epilogue per block.
// LDS 2*(256+192)*64*2B = 112 KB.
// ---------------------------------------------------------------------------
__global__ __launch_bounds__(512, 2) void gemm_qkv_kernel(
    const bf16* __restrict__ xnt, const bf16* __restrict__ Wb,
    const float* __restrict__ bs, bf16* __restrict__ qkT, bf16* __restrict__ vv)
{
  const int bid = blockIdx.x;
  const int swz = (bid & 7) * 32 + (bid >> 3);   // bijective: 256 = 8 * 32
  const int bxn = swz >> 4, bym = swz & 15;      // per XCD: 2 N-panels x 16 M
  const int n0 = bxn * 192, m0 = bym * 256;
  const int head = bxn;

  __shared__ __align__(16) bf16 Al[2][256 * 64];
  __shared__ __align__(16) bf16 Bl[2][192 * 64];

  const int tid  = threadIdx.x;
  const int wave = tid >> 6, lane = tid & 63;
  const int quad = lane >> 4, l15 = lane & 15;
  const int wr = wave >> 2, wc = wave & 3;
  const int lrow = lane >> 3, lp = lane & 7;
  const int sc8 = (lp ^ lrow) << 3;   // pre-swizzled source chunk (elements)

  // 7 DMA calls stage one full K-tile (A: 4x64 rows, B: 3x64 rows).
  #define STAGE(bufn, kt) do {                                                \
    _Pragma("unroll")                                                         \
    for (int c = 0; c < 4; ++c)                                               \
      GLOAD_LDS16(xnt + (size_t)(m0 + c * 64 + wave * 8 + lrow) * 1024 +      \
                      (size_t)(kt) * 64 + sc8,                                \
                  &Al[bufn][(c * 64 + wave * 8) * 64]);                       \
    _Pragma("unroll")                                                         \
    for (int c = 0; c < 3; ++c)                                               \
      GLOAD_LDS16(Wb + (size_t)(n0 + c * 64 + wave * 8 + lrow) * 1024 +       \
                      (size_t)(kt) * 64 + sc8,                                \
                  &Bl[bufn][(c * 64 + wave * 8) * 64]);                       \
  } while (0)

  F4 acc[8][3];
  #pragma unroll
  for (int i = 0; i < 8; ++i)
    #pragma unroll
    for (int j = 0; j < 3; ++j) acc[i][j].v = (f32x4){0.f, 0.f, 0.f, 0.f};

  STAGE(0, 0);
  __syncthreads();

  for (int t = 0; t < 16; ++t) {
    const int cb = t & 1;

    // 1) All LDS fragment reads of the current buffer, issued first.
    bf16x8 af[2][8], bfr[2][3];
    #pragma unroll
    for (int kk = 0; kk < 2; ++kk) {
      #pragma unroll
      for (int nt = 0; nt < 3; ++nt)
        bfr[kk][nt] = SWZ(Bl[cb], wc * 48 + nt * 16 + l15, kk * 4 + quad);
      #pragma unroll
      for (int mt = 0; mt < 8; ++mt)
        af[kk][mt] = SWZ(Al[cb], wr * 128 + mt * 16 + l15, kk * 4 + quad);
    }

    // 2) Prefetch next K-tile into the other buffer.
    if (t + 1 < 16) STAGE(cb ^ 1, t + 1);

    // 3) MFMA cluster (same K accumulation order as previous rounds).
    #pragma unroll
    for (int kk = 0; kk < 2; ++kk)
      #pragma unroll
      for (int mt = 0; mt < 8; ++mt)
        #pragma unroll
        for (int nt = 0; nt < 3; ++nt)
          acc[mt][nt].v = __builtin_amdgcn_mfma_f32_16x16x32_bf16(
              af[kk][mt], bfr[kk][nt], acc[mt][nt].v, 0, 0, 0);

    // 4) Single barrier: drains DMA (next tile ready) + all waves done
    //    reading buf[cb] (it is overwritten next tile).
    __syncthreads();
  }
  #undef STAGE

  // Epilogue: block covers exactly one 192-col head group.
  const int z  = m0 >> 10;
  const int tb = (m0 & 1023) + wr * 128;
  #pragma unroll
  for (int nt = 0; nt < 3; ++nt) {
    const int r192 = wc * 48 + nt * 16;     // 0..176, wave-uniform
    const float bb = bs[n0 + r192 + l15];
    if (r192 < 128) {
      const int col = head * 128 + r192 + l15;
      #pragma unroll
      for (int mt = 0; mt < 8; ++mt)
        #pragma unroll
        for (int r = 0; r < 4; ++r) {
          const int m = m0 + wr * 128 + mt * 16 + quad * 4 + r;
          qkT[(size_t)m * 2048 + col] = (bf16)(acc[mt][nt].e[r] + bb);
        }
    } else {
      bf16* vrow = vv + ((size_t)z * 1024 + head * 64 + (r192 - 128) + l15) * 1024;
      #pragma unroll
      for (int mt = 0; mt < 8; ++mt) {
        B4 pk;
        #pragma unroll
        for (int r = 0; r < 4; ++r) pk.e[r] = (bf16)(acc[mt][nt].e[r] + bb);
        *(bf16x4*)&vrow[tb + mt * 16 + quad * 4] = pk.v;
      }
    }
  }
}

// ---------------------------------------------------------------------------
// Kernel 4: proj GEMM, 64x64 tiles -> grid (16,16,4) = 1024 blocks = 4/CU.
// DMA staging + swizzled LDS, BK=64. Wave-tile 32x32 (2x2 MFMA frags).
// out = acc + bias + residual (fp32).
// ---------------------------------------------------------------------------
__global__ __launch_bounds__(256) void gemm_proj_kernel(
    const bf16* __restrict__ Pb, const bf16* __restrict__ Bt,
    float* __restrict__ Cf, const float* __restrict__ bias,
    const float* __restrict__ resf)
{
  const int z = blockIdx.z;
  Bt   += (size_t)z * 1024 * 1024;
  Cf   += (size_t)z * 1024 * 1024;
  resf += (size_t)z * 1024 * 1024;
  const int n0 = blockIdx.x * 64, m0 = blockIdx.y * 64;

  __shared__ __align__(16) bf16 Al[64 * 64];
  __shared__ __align__(16) bf16 Bl[64 * 64];

  const int tid  = threadIdx.x;
  const int wave = tid >> 6, lane = tid & 63;
  const int quad = lane >> 4, l15 = lane & 15;
  const int wr = wave >> 1, wc = wave & 1;
  const int lrow = lane >> 3, lp = lane & 7;

  F4 acc[2][2];
  #pragma unroll
  for (int i = 0; i < 2; ++i)
    #pragma unroll
    for (int j = 0; j < 2; ++j) acc[i][j].v = (f32x4){0.f, 0.f, 0.f, 0.f};

  for (int k0 = 0; k0 < 1024; k0 += 64) {
    #pragma unroll
    for (int call = 0; call < 2; ++call) {
      const int row = wave * 16 + call * 8 + lrow;
      const int c8  = lp ^ (row & 7);
      GLOAD_LDS16(Pb + (size_t)(m0 + row) * 1024 + k0 + c8 * 8,
                  &Al[(wave * 16 + call * 8) * 64]);
      GLOAD_LDS16(Bt + (size_t)(n0 + row) * 1024 + k0 + c8 * 8,
                  &Bl[(wave * 16 + call * 8) * 64]);
    }
    __syncthreads();

    #pragma unroll
    for (int ks = 0; ks < 2; ++ks) {
      bf16x8 af[2], bfr[2];
      #pragma unroll
      for (int mt = 0; mt < 2; ++mt)
        af[mt] = SWZ(Al, wr * 32 + mt * 16 + l15, ks * 4 + quad);
      #pragma unroll
      for (int nt = 0; nt < 2; ++nt)
        bfr[nt] = SWZ(Bl, wc * 32 + nt * 16 + l15, ks * 4 + quad);
      #pragma unroll
      for (int mt = 0; mt < 2; ++mt)
        #pragma unroll
        for (int nt = 0; nt < 2; ++nt)
          acc[mt][nt].v = __builtin_amdgcn_mfma_f32_16x16x32_bf16(
              af[mt], bfr[nt], acc[mt][nt].v, 0, 0, 0);
    }
    __syncthreads();
  }

  #pragma unroll
  for (int mt = 0; mt < 2; ++mt) {
    #pragma unroll
    for (int r = 0; r < 4; ++r) {
      const int m = m0 + wr * 32 + mt * 16 + quad * 4 + r;
      const float bb = bias[m];
      #pragma unroll
      for (int nt = 0; nt < 2; ++nt) {
        const int n = n0 + wc * 32 + nt * 16 + l15;
        Cf[(size_t)m * 1024 + n] = acc[mt][nt].e[r] + bb + resf[(size_t)m * 1024 + n];
      }
    }
  }
}

// ---------------------------------------------------------------------------
// Kernel 3: attention, S^T + no-max softmax, 128-t blocks: each wave owns
// TWO independent 16-t bands -> k/v fragments read ONCE per wave-chunk and
// reused by both bands, two independent S->exp->PV chains interleave for
// latency hiding, k/v staged per 128 t. grid (16,8,4) = 512 blocks.
// LDS: qP 16K (q then P bands) + kl 2x8K + vl 2x8K = 48 KB.
// ---------------------------------------------------------------------------
__global__ __launch_bounds__(256) void attn_kernel(
    const bf16* __restrict__ qkTin, const bf16* __restrict__ vmat,
    bf16* __restrict__ aout)
{
  const int h = blockIdx.x, tt = blockIdx.y, z = blockIdx.z;
  const bf16* qk = qkTin + (size_t)z * 1024 * 2048;
  const bf16* vp = vmat + (size_t)z * 1024 * 1024 + (size_t)(h * 64) * 1024;
  aout += (size_t)z * 1024 * 1024;
  const int t0 = tt * 128;

  __shared__ __align__(16) bf16 qP[128 * 64];     // q rows (init) then P bands
  __shared__ __align__(16) bf16 kl[2][64 * 64];
  __shared__ __align__(16) bf16 vl[2][64 * 64];

  const int tid  = threadIdx.x;
  const int wave = tid >> 6, lane = tid & 63;
  const int quad = lane >> 4, l15 = lane & 15;
  const int lrow = lane >> 3, lp = lane & 7;

  #pragma unroll
  for (int c = 0; c < 4; ++c) {
    const int row = wave * 32 + c * 8 + lrow;
    const int c8  = lp ^ (row & 7);
    GLOAD_LDS16(qk + (size_t)(t0 + row) * 2048 + h * 128 + c8 * 8,
                &qP[(wave * 32 + c * 8) * 64]);
  }
  const int r0 = wave * 16 + lrow, r1 = wave * 16 + 8 + lrow;
  const int c80 = lp ^ (r0 & 7), c81 = lp ^ (r1 & 7);
  GLOAD_LDS16(qk + (size_t)r0 * 2048 + h * 128 + 64 + c80 * 8, &kl[0][(wave * 16) * 64]);
  GLOAD_LDS16(qk + (size_t)r1 * 2048 + h * 128 + 64 + c81 * 8, &kl[0][(wave * 16 + 8) * 64]);
  GLOAD_LDS16(vp + (size_t)r0 * 1024 + c80 * 8, &vl[0][(wave * 16) * 64]);
  GLOAD_LDS16(vp + (size_t)r1 * 1024 + c81 * 8, &vl[0][(wave * 16 + 8) * 64]);
  __syncthreads();

  bf16x8 bq0[2], bq1[2];
  int prow[2];
  #pragma unroll
  for (int b = 0; b < 2; ++b) {
    const int Rq = wave * 32 + b * 16 + l15;
    bq0[b] = SWZ(qP, Rq, quad);
    bq1[b] = SWZ(qP, Rq, quad + 4);
    prow[b] = Rq;
  }

  float l_i[2] = {0.f, 0.f};
  F4 oacc[2][4];
  #pragma unroll
  for (int b = 0; b < 2; ++b)
    #pragma unroll
    for (int ct = 0; ct < 4; ++ct) oacc[b][ct].v = (f32x4){0.f, 0.f, 0.f, 0.f};

  const int pq8 = (quad & 1) * 4;

  int buf = 0;
  for (int s0 = 0; s0 < 1024; s0 += 64) {
    if (s0 + 64 < 1024) {
      const int nb = buf ^ 1, sn = s0 + 64;
      GLOAD_LDS16(qk + (size_t)(sn + r0) * 2048 + h * 128 + 64 + c80 * 8,
                  &kl[nb][(wave * 16) * 64]);
      GLOAD_LDS16(qk + (size_t)(sn + r1) * 2048 + h * 128 + 64 + c81 * 8,
                  &kl[nb][(wave * 16 + 8) * 64]);
      GLOAD_LDS16(vp + (size_t)r0 * 1024 + sn + c80 * 8, &vl[nb][(wave * 16) * 64]);
      GLOAD_LDS16(vp + (size_t)r1 * 1024 + sn + c81 * 8, &vl[nb][(wave * 16 + 8) * 64]);
    }

    bf16x8 ak0[4], ak1[4], bv[2][4];
    #pragma unroll
    for (int st = 0; st < 4; ++st) {
      const int Rk = st * 16 + l15;
      ak0[st] = SWZ(kl[buf], Rk, quad);
      ak1[st] = SWZ(kl[buf], Rk, quad + 4);
    }
    #pragma unroll
    for (int ks = 0; ks < 2; ++ks)
      #pragma unroll
      for (int ct = 0; ct < 4; ++ct)
        bv[ks][ct] = SWZ(vl[buf], ct * 16 + l15, ks * 4 + quad);

    #pragma unroll
    for (int b = 0; b < 2; ++b) {
      F4 sacc[4];
      #pragma unroll
      for (int st = 0; st < 4; ++st) sacc[st].v = (f32x4){0.f, 0.f, 0.f, 0.f};
      #pragma unroll
      for (int st = 0; st < 4; ++st) {
        sacc[st].v = __builtin_amdgcn_mfma_f32_16x16x32_bf16(ak0[st], bq0[b], sacc[st].v, 0, 0, 0);
        sacc[st].v = __builtin_amdgcn_mfma_f32_16x16x32_bf16(ak1[st], bq1[b], sacc[st].v, 0, 0, 0);
      }

      bf16* const pbase = &qP[(size_t)prow[b] * 64];
      #pragma unroll
      for (int st = 0; st < 4; ++st) {
        B4 pk;
        #pragma unroll
        for (int r = 0; r < 4; ++r) {
          const float p = __builtin_amdgcn_exp2f(sacc[st].e[r]);
          l_i[b] += p;
          pk.e[r] = (bf16)p;
        }
        const int c8 = (st * 2 + (quad >> 1)) ^ (prow[b] & 7);
        *(bf16x4*)(pbase + (c8 << 3) + pq8) = pk.v;
      }

      #pragma unroll
      for (int ks = 0; ks < 2; ++ks) {
        const bf16x8 ap = SWZ(qP, prow[b], ks * 4 + quad);
        #pragma unroll
        for (int ct = 0; ct < 4; ++ct)
          oacc[b][ct].v = __builtin_amdgcn_mfma_f32_16x16x32_bf16(
              ap, bv[ks][ct], oacc[b][ct].v, 0, 0, 0);
      }
    }
    __syncthreads();
    buf ^= 1;
  }

  #pragma unroll
  for (int b = 0; b < 2; ++b) {
    float li = l_i[b];
    li += __shfl_xor(li, 16);
    li += __shfl_xor(li, 32);
    const float inv = 1.f / li;
    float iv[4];
    #pragma unroll
    for (int r = 0; r < 4; ++r) iv[r] = __shfl(inv, quad * 4 + r);
    #pragma unroll
    for (int r = 0; r < 4; ++r) {
      const int t = t0 + wave * 32 + b * 16 + quad * 4 + r;
      #pragma unroll
      for (int ct = 0; ct < 4; ++ct)
        aout[(size_t)t * 1024 + h * 64 + ct * 16 + l15] = (bf16)(oacc[b][ct].e[r] * iv[r]);
    }
  }
}

// ---------------------------------------------------------------------------
// ws layout:
//   xnt [b][t][c] : ws[ 0,  8 MB)
//   qkT [b][t][n] : ws[ 8, 24 MB)
//   v   [b][ov][t]: ws[24, 32 MB)
//   a^T [b][t][c] : ws[32, 40 MB)
//   Wb / Pb / bs  : ws[40, 48 MB) + 12 KB
// ---------------------------------------------------------------------------
extern "C" void kernel_launch(void* const* d_in, const int* in_sizes, int n_in,
                              void* d_out, int out_size, void* d_ws, size_t ws_size,
                              hipStream_t stream)
{
  const float* x    = (const float*)d_in[0];
  const float* nw   = (const float*)d_in[1];
  const float* nb   = (const float*)d_in[2];
  const float* qkvw = (const float*)d_in[3];
  const float* qkvb = (const float*)d_in[4];
  const float* pw   = (const float*)d_in[5];
  const float* pb   = (const float*)d_in[6];
  float* out = (float*)d_out;

  const long M1 = 1024L * 1024L;
  bf16*  xnt = (bf16*)d_ws;
  bf16*  qkT = xnt + 4 * M1;
  bf16*  vv  = xnt + 12 * M1;
  bf16*  at  = xnt + 16 * M1;
  bf16*  Wb  = xnt + 20 * M1;
  bf16*  Pb  = xnt + 23 * M1;
  float* bs  = (float*)(xnt + 24 * M1);

  conv_w_kernel<<<dim3(4096), dim3(256), 0, stream>>>(qkvw, qkvb, pw, Wb, Pb, bs);
  gn_t_kernel<<<dim3(128), dim3(256), 0, stream>>>(x, nw, nb, xnt);
  gemm_qkv_kernel<<<dim3(256), dim3(512), 0, stream>>>(xnt, Wb, bs, qkT, vv);
  attn_kernel<<<dim3(16, 8, 4), dim3(256), 0, stream>>>(qkT, vv, at);
  gemm_proj_kernel<<<dim3(16, 16, 4), dim3(256), 0, stream>>>(Pb, at, out, pb, x);
}